// Round 14
// baseline (141.209 us; speedup 1.0000x reference)
//
#include <hip/hip_runtime.h>

#define D    2048
#define NB   32
#define BD   64
#define HD   128
#define WSZ  (NB * HD * BD)     // 262144 elems per weight matrix
#define TSZ  (16384 * 64)       // 1048576 elems per activation block-tile

typedef __attribute__((ext_vector_type(8))) short short8;
typedef __attribute__((ext_vector_type(4))) float floatx4;

static __device__ __forceinline__ unsigned short f2bf(float f) {
  union { float f; unsigned u; } v; v.f = f;
  return (unsigned short)((v.u + 0x7FFFu + ((v.u >> 16) & 1u)) >> 16);
}
static __device__ __forceinline__ float bf2f(unsigned short h) {
  union { unsigned u; float f; } v; v.u = ((unsigned)h) << 16;
  return v.f;
}
static __device__ __forceinline__ unsigned fbits(float f) {
  union { float f; unsigned u; } v; v.f = f; return v.u;
}
// truncation bf16 (scalar) and bf16x2 pack (validated r9-r13, absmax 384 < 586)
static __device__ __forceinline__ unsigned short tbf(float f) {
  return (unsigned short)(fbits(f) >> 16);
}
static __device__ __forceinline__ unsigned pkt(float a, float b) {
  return __builtin_amdgcn_perm(fbits(b), fbits(a), 0x07060302u);
}
static __device__ __forceinline__ float fast_exp2(float x) {
  float r; asm("v_exp_f32 %0, %1" : "=v"(r) : "v"(x)); return r;
}
static __device__ __forceinline__ float fast_rcp(float x) {
  float r; asm("v_rcp_f32 %0, %1" : "=v"(r) : "v"(x)); return r;
}
// sigmoid-form GELU (validated r1-r13)
static __device__ __forceinline__ float gelu_f(float x) {
  float x2 = x * x;
  float w  = __builtin_fmaf(x2, -0.102943695f, -2.3022083f);
  float e  = fast_exp2(x * w);
  return x * fast_rcp(1.0f + e);
}

// ---------------------------------------------------------------------------
// mlp0 (r14): 256 rows/WG (grid 2048) — weights staged once per 256 rows
// (r13 audit: per-WG fixed cost ~8.4us vs ~2us of real work; halve WG count).
// Tile i (0..3) rows = chunk*256 + i*64 + wv*16 + lr. 2-deep reg prefetch
// with compiler fences (r10 pattern). Olds transpose buffer reused per
// 128-row half (tiles {0,1} -> writeout -> tiles {2,3} -> writeout).
// ---------------------------------------------------------------------------
__global__ __launch_bounds__(256, 3) void mlp0_k(
    const float* __restrict__ xf,
    unsigned short* __restrict__ Yt0,        // [n][64][16384]
    const unsigned short* __restrict__ Wt1,
    const unsigned short* __restrict__ Wt2,
    const float* __restrict__ b1, const float* __restrict__ b2) {
  __shared__ unsigned short Wlds[16384];     // 32 KB
  __shared__ unsigned short Olds[64 * 128];  // 16 KB
  __shared__ float Blds[192];
  const int n     = blockIdx.x & 31;
  const int chunk = blockIdx.x >> 5;         // 0..63, 256 rows each
  const int t = threadIdx.x, l = t & 63, wv = t >> 6;
  const int lr = l & 15, q = l >> 4;
  const int sw = (lr & 7) << 3;
  const size_t rowbase = (size_t)chunk * 256;

  // (1) weight-staging loads
  const unsigned short* s1 = Wt1 + n * 8192;
  const unsigned short* s2 = Wt2 + n * 8192;
  short8 sv1[4], sv2[4];
#pragma unroll
  for (int j = 0; j < 4; ++j) {
    sv1[j] = *(const short8*)&s1[(j * 256 + t) * 8];
    sv2[j] = *(const short8*)&s2[(j * 256 + t) * 8];
  }
  // (2) bias loads
  float bv = 0.f;
  if (t < 128)      bv = b1[n * HD + t];
  else if (t < 192) bv = b2[n * BD + (t - 128)];
  // (3) x tiles 0,1
  float4 uf[2][4];
#pragma unroll
  for (int p = 0; p < 2; ++p) {
    const float* xr = xf + (rowbase + p * 64 + wv * 16 + lr) * D + n * BD + q * 8;
    uf[p][0] = *(const float4*)(xr);      uf[p][1] = *(const float4*)(xr + 4);
    uf[p][2] = *(const float4*)(xr + 32); uf[p][3] = *(const float4*)(xr + 36);
  }
  // (4) fence, (5) LDS writes + barrier
  asm volatile("" ::: "memory");
#pragma unroll
  for (int j = 0; j < 4; ++j) {
    *(short8*)&Wlds[(j * 256 + t) * 8]        = sv1[j];
    *(short8*)&Wlds[8192 + (j * 256 + t) * 8] = sv2[j];
  }
  if (t < 192) Blds[t] = bv;
  __syncthreads();

  const unsigned short* w1p0 = &Wlds[lr * 64 + ((q * 8) ^ sw)];
  const unsigned short* w1p1 = &Wlds[lr * 64 + ((32 + q * 8) ^ sw)];
  const unsigned short* w2p0 = &Wlds[8192 + lr * 128 + ((q * 8) ^ sw)];
  const unsigned short* w2p1 = &Wlds[8192 + lr * 128 + ((32 + q * 8) ^ sw)];

#pragma unroll
  for (int half = 0; half < 2; ++half) {
#pragma unroll
    for (int it = 0; it < 2; ++it) {
      const int i    = half * 2 + it;
      const int slot = i & 1;
      short8 xb0, xb1;
      {
        union { unsigned u[4]; short8 s; } c0, c1;
        c0.u[0] = pkt(uf[slot][0].x, uf[slot][0].y);
        c0.u[1] = pkt(uf[slot][0].z, uf[slot][0].w);
        c0.u[2] = pkt(uf[slot][1].x, uf[slot][1].y);
        c0.u[3] = pkt(uf[slot][1].z, uf[slot][1].w);
        c1.u[0] = pkt(uf[slot][2].x, uf[slot][2].y);
        c1.u[1] = pkt(uf[slot][2].z, uf[slot][2].w);
        c1.u[2] = pkt(uf[slot][3].x, uf[slot][3].y);
        c1.u[3] = pkt(uf[slot][3].z, uf[slot][3].w);
        xb0 = c0.s; xb1 = c1.s;
      }
      // prefetch tile i+2 into the freed slot, pinned by fence
      if (i < 2) {
        const float* xr = xf + (rowbase + (i + 2) * 64 + wv * 16 + lr) * D + n * BD + q * 8;
        uf[slot][0] = *(const float4*)(xr);      uf[slot][1] = *(const float4*)(xr + 4);
        uf[slot][2] = *(const float4*)(xr + 32); uf[slot][3] = *(const float4*)(xr + 36);
        asm volatile("" ::: "memory");
      }

      floatx4 acc2[4];
#pragma unroll
      for (int ot = 0; ot < 4; ++ot) {
        const float4 bb = *(const float4*)&Blds[128 + ot * 16 + q * 4];
        floatx4 v; v[0] = bb.x; v[1] = bb.y; v[2] = bb.z; v[3] = bb.w;
        acc2[ot] = v;
      }
#pragma unroll
      for (int hf = 0; hf < 2; ++hf) {
        floatx4 acc1[4];
#pragma unroll
        for (int ot = 0; ot < 4; ++ot) {
          const float4 bb = *(const float4*)&Blds[hf * 64 + ot * 16 + q * 4];
          floatx4 v; v[0] = bb.x; v[1] = bb.y; v[2] = bb.z; v[3] = bb.w;
          acc1[ot] = v;
        }
#pragma unroll
        for (int ot = 0; ot < 4; ++ot) {
          const int off = (hf * 64 + ot * 16) * 64;
          short8 a0 = *(const short8*)&w1p0[off];
          short8 a1 = *(const short8*)&w1p1[off];
          acc1[ot] = __builtin_amdgcn_mfma_f32_16x16x32_bf16(a0, xb0, acc1[ot], 0, 0, 0);
          acc1[ot] = __builtin_amdgcn_mfma_f32_16x16x32_bf16(a1, xb1, acc1[ot], 0, 0, 0);
        }
        union { unsigned u[4]; short8 s; } hb0, hb1;
        hb0.u[0] = pkt(gelu_f(acc1[0][0]), gelu_f(acc1[0][1]));
        hb0.u[1] = pkt(gelu_f(acc1[0][2]), gelu_f(acc1[0][3]));
        hb0.u[2] = pkt(gelu_f(acc1[1][0]), gelu_f(acc1[1][1]));
        hb0.u[3] = pkt(gelu_f(acc1[1][2]), gelu_f(acc1[1][3]));
        hb1.u[0] = pkt(gelu_f(acc1[2][0]), gelu_f(acc1[2][1]));
        hb1.u[1] = pkt(gelu_f(acc1[2][2]), gelu_f(acc1[2][3]));
        hb1.u[2] = pkt(gelu_f(acc1[3][0]), gelu_f(acc1[3][1]));
        hb1.u[3] = pkt(gelu_f(acc1[3][2]), gelu_f(acc1[3][3]));
#pragma unroll
        for (int ot = 0; ot < 4; ++ot) {
          const int off = ot * 16 * 128 + hf * 64;
          short8 w0 = *(const short8*)&w2p0[off];
          short8 w1 = *(const short8*)&w2p1[off];
          acc2[ot] = __builtin_amdgcn_mfma_f32_16x16x32_bf16(w0, hb0.s, acc2[ot], 0, 0, 0);
          acc2[ot] = __builtin_amdgcn_mfma_f32_16x16x32_bf16(w1, hb1.s, acc2[ot], 0, 0, 0);
        }
      }
      // scatter into Olds: rl in [0,128) for this half
      const int rl = it * 64 + wv * 16 + lr;
#pragma unroll
      for (int ot = 0; ot < 4; ++ot) {
#pragma unroll
        for (int e = 0; e < 4; ++e) {
          const int fo = ot * 16 + q * 4 + e;
          Olds[fo * 128 + (rl ^ ((fo & 7) << 3))] = tbf(acc2[ot][e]);
        }
      }
    }
    __syncthreads();   // Olds complete for this half
    // transposed write-out: rows rowbase + half*128 + r4
    const int j = t & 63, w = t >> 6;
#pragma unroll
    for (int ii = 0; ii < 8; ++ii) {
      const int fo = w * 16 + ii * 2 + (j >> 5);
      const int r4 = (j & 31) * 4;
      const int G  = (fo & 7) << 3;
      uint2 v = *(const uint2*)&Olds[fo * 128 + (r4 ^ G)];
      *(uint2*)(Yt0 + (size_t)n * TSZ + (size_t)fo * 16384 + rowbase + half * 128 + r4) = v;
    }
    if (half == 0) __syncthreads();   // Olds reusable for half 1
  }
}

// ---------------------------------------------------------------------------
// mlp1 (r14): 256 rows/WG (grid 2048). Xl (16 KB) staged per 128-row half;
// half-2 global loads issued BEFORE half-1 compute (fence), LDS-written
// after the post-compute barrier -> latency hidden, single buffer.
// Permute mapping unchanged (validated r11-r13).
// ---------------------------------------------------------------------------
__global__ __launch_bounds__(256, 3) void mlp1_k(
    const unsigned short* __restrict__ Yt0,   // [n][64][16384]
    unsigned short* __restrict__ Yt1,         // [np][16384][64]
    const unsigned short* __restrict__ Wt1,
    const unsigned short* __restrict__ Wt2,
    const float* __restrict__ b1, const float* __restrict__ b2) {
  __shared__ unsigned short Wlds[16384];       // 32 KB
  __shared__ unsigned short Xl[2 * 128 * 32];  // 16 KB (one 128-row half)
  __shared__ float Blds[192];
  const int np    = blockIdx.x & 31;
  const int chunk = blockIdx.x >> 5;           // 0..63
  const int t = threadIdx.x, l = t & 63, wv = t >> 6;
  const int lr = l & 15, q = l >> 4;
  const int sw = (lr & 7) << 3;
  const size_t rowbase = (size_t)chunk * 256;

  // (1) weight-staging loads
  const unsigned short* s1 = Wt1 + np * 8192;
  const unsigned short* s2 = Wt2 + np * 8192;
  short8 sv1[4], sv2[4];
#pragma unroll
  for (int j = 0; j < 4; ++j) {
    sv1[j] = *(const short8*)&s1[(j * 256 + t) * 8];
    sv2[j] = *(const short8*)&s2[(j * 256 + t) * 8];
  }
  // (2) bias loads
  float bv = 0.f;
  if (t < 128)      bv = b1[np * HD + t];
  else if (t < 192) bv = b2[np * BD + (t - 128)];
  // (3) Xl half-0 stage loads (chunk c=(p,n'), 4 threads/chunk, 64B each)
  const int c = t >> 2, sub = t & 3;
  const int sp = c >> 5, sn = c & 31;
  const unsigned short* src0 = Yt0 + (size_t)sn * TSZ + (size_t)(sp * 32 + np) * 16384
                               + rowbase + sub * 32;
  short8 sx[4];
#pragma unroll
  for (int m = 0; m < 4; ++m) sx[m] = *(const short8*)(src0 + m * 8);

  asm volatile("" ::: "memory");
#pragma unroll
  for (int j = 0; j < 4; ++j) {
    *(short8*)&Wlds[(j * 256 + t) * 8]        = sv1[j];
    *(short8*)&Wlds[8192 + (j * 256 + t) * 8] = sv2[j];
  }
  if (t < 192) Blds[t] = bv;
#pragma unroll
  for (int m = 0; m < 4; ++m) {
#pragma unroll
    for (int k = 0; k < 8; ++k) {
      const int row = sub * 32 + m * 8 + k;
      Xl[sp * 4096 + row * 32 + (sn ^ (((row >> 1) & 3) << 3))] = (unsigned short)sx[m][k];
    }
  }
  __syncthreads();

  const unsigned short* w1p0 = &Wlds[lr * 64 + ((q * 8) ^ sw)];
  const unsigned short* w1p1 = &Wlds[lr * 64 + ((32 + q * 8) ^ sw)];
  const unsigned short* w2p0 = &Wlds[8192 + lr * 128 + ((q * 8) ^ sw)];
  const unsigned short* w2p1 = &Wlds[8192 + lr * 128 + ((32 + q * 8) ^ sw)];
  const int p = lr & 1;

#pragma unroll
  for (int half = 0; half < 2; ++half) {
    // issue half-1 stage loads early; consumed after the post-compute barrier
    short8 sx2[4];
    if (half == 0) {
      const unsigned short* src1 = src0 + 128;   // rows rowbase+128
#pragma unroll
      for (int m = 0; m < 4; ++m) sx2[m] = *(const short8*)(src1 + m * 8);
      asm volatile("" ::: "memory");
    }
#pragma unroll
    for (int i = 0; i < 2; ++i) {
      const int rloc = (wv * 32 + i * 16 + lr) & ~1;
      const int g0   = ((rloc >> 1) & 3) << 3;
      short8 xb0 = *(const short8*)&Xl[p * 4096 + rloc * 32 + ((q * 8) ^ g0)];
      short8 xb1 = *(const short8*)&Xl[p * 4096 + (rloc + 1) * 32 + ((q * 8) ^ g0)];

      floatx4 acc2[4];
#pragma unroll
      for (int ot = 0; ot < 4; ++ot) {
        const float4 bb = *(const float4*)&Blds[128 + ot * 16 + q * 4];
        floatx4 v; v[0] = bb.x; v[1] = bb.y; v[2] = bb.z; v[3] = bb.w;
        acc2[ot] = v;
      }
#pragma unroll
      for (int hf = 0; hf < 2; ++hf) {
        floatx4 acc1[4];
#pragma unroll
        for (int ot = 0; ot < 4; ++ot) {
          const float4 bb = *(const float4*)&Blds[hf * 64 + ot * 16 + q * 4];
          floatx4 v; v[0] = bb.x; v[1] = bb.y; v[2] = bb.z; v[3] = bb.w;
          acc1[ot] = v;
        }
#pragma unroll
        for (int ot = 0; ot < 4; ++ot) {
          const int off = (hf * 64 + ot * 16) * 64;
          short8 a0 = *(const short8*)&w1p0[off];
          short8 a1 = *(const short8*)&w1p1[off];
          acc1[ot] = __builtin_amdgcn_mfma_f32_16x16x32_bf16(a0, xb0, acc1[ot], 0, 0, 0);
          acc1[ot] = __builtin_amdgcn_mfma_f32_16x16x32_bf16(a1, xb1, acc1[ot], 0, 0, 0);
        }
        union { unsigned u[4]; short8 s; } hb0, hb1;
        hb0.u[0] = pkt(gelu_f(acc1[0][0]), gelu_f(acc1[0][1]));
        hb0.u[1] = pkt(gelu_f(acc1[0][2]), gelu_f(acc1[0][3]));
        hb0.u[2] = pkt(gelu_f(acc1[1][0]), gelu_f(acc1[1][1]));
        hb0.u[3] = pkt(gelu_f(acc1[1][2]), gelu_f(acc1[1][3]));
        hb1.u[0] = pkt(gelu_f(acc1[2][0]), gelu_f(acc1[2][1]));
        hb1.u[1] = pkt(gelu_f(acc1[2][2]), gelu_f(acc1[2][3]));
        hb1.u[2] = pkt(gelu_f(acc1[3][0]), gelu_f(acc1[3][1]));
        hb1.u[3] = pkt(gelu_f(acc1[3][2]), gelu_f(acc1[3][3]));
#pragma unroll
        for (int ot = 0; ot < 4; ++ot) {
          const int off = ot * 16 * 128 + hf * 64;
          short8 w0 = *(const short8*)&w2p0[off];
          short8 w1 = *(const short8*)&w2p1[off];
          acc2[ot] = __builtin_amdgcn_mfma_f32_16x16x32_bf16(w0, hb0.s, acc2[ot], 0, 0, 0);
          acc2[ot] = __builtin_amdgcn_mfma_f32_16x16x32_bf16(w1, hb1.s, acc2[ot], 0, 0, 0);
        }
      }
      // store block-tile (RNE, final-quality rounding)
      unsigned short* yo = Yt1 + (size_t)np * TSZ
                         + (rowbase + half * 128 + wv * 32 + i * 16 + lr) * 64;
#pragma unroll
      for (int ot = 0; ot < 4; ++ot) {
        ushort4 ov;
        ov.x = f2bf(acc2[ot][0]);
        ov.y = f2bf(acc2[ot][1]);
        ov.z = f2bf(acc2[ot][2]);
        ov.w = f2bf(acc2[ot][3]);
        *(ushort4*)&yo[ot * 16 + q * 4] = ov;
      }
    }
    if (half == 0) {
      __syncthreads();   // all Xl half-0 reads done (+ sx2 loads drained)
#pragma unroll
      for (int m = 0; m < 4; ++m) {
#pragma unroll
        for (int k = 0; k < 8; ++k) {
          const int row = sub * 32 + m * 8 + k;
          Xl[sp * 4096 + row * 32 + (sn ^ (((row >> 1) & 3) << 3))] = (unsigned short)sx2[m][k];
        }
      }
      __syncthreads();   // Xl half-1 staged
    }
  }
}

// ---------------------------------------------------------------------------
// unpermute_k (unchanged from r12/r13): Yt1 block-tile -> f32 row-major out,
// 1KB-contiguous writes per wave instruction.
// ---------------------------------------------------------------------------
__global__ __launch_bounds__(256) void unpermute_k(const unsigned short* __restrict__ Y,
                                                   float* __restrict__ out) {
  __shared__ unsigned short L[32 * 512];   // 32KB
  const int t = threadIdx.x, w = t >> 6, j = t & 63;
  const size_t r0 = (size_t)blockIdx.x * 8;
#pragma unroll
  for (int c = 0; c < 8; ++c) {
    const int n = w * 8 + c;
    short8 v = *(const short8*)(Y + (size_t)n * TSZ + r0 * 64 + j * 8);
    const int row = j >> 3;
    const int gp = (j & 7) ^ ((n + row) & 7);
    *(short8*)&L[n * 512 + row * 64 + gp * 8] = v;
  }
  __syncthreads();
#pragma unroll
  for (int p = 0; p < 2; ++p) {
    const int rloc = w * 2 + p;
    float* op = out + (r0 + rloc) * (size_t)D;
#pragma unroll
    for (int i = 0; i < 8; ++i) {
      const int cbase = i * 256 + j * 4;
      float4 f;
#pragma unroll
      for (int e = 0; e < 4; ++e) {
        const int cc   = cbase + e;
        const int npp  = cc >> 6, fp = cc & 63;
        const int n    = fp & 31;
        const int srow = (rloc & ~1) | (fp >> 5);
        const int scol = (rloc & 1) * 32 + npp;
        const int g    = ((scol >> 3) ^ ((n + srow) & 7));
        const float v  = bf2f(L[n * 512 + srow * 64 + g * 8 + (scol & 7)]);
        if      (e == 0) f.x = v;
        else if (e == 1) f.y = v;
        else if (e == 2) f.z = v;
        else             f.w = v;
      }
      *(float4*)&op[cbase] = f;
    }
  }
}

// W [n][R][C] f32 -> Wt [n][C][R] bf16, transposed + XOR-swizzled.
// W2 (odd segs) additionally k-slot-permuted (zero-DS H; validated r7-r13).
__global__ void prep_w_all(const float* __restrict__ W1_0, const float* __restrict__ W2_0,
                           const float* __restrict__ W1_1, const float* __restrict__ W2_1,
                           unsigned short* __restrict__ dst) {
  const int seg = blockIdx.x >> 10;
  const int id  = ((blockIdx.x & 1023) << 8) | threadIdx.x;
  const float* W; int R;
  if      (seg == 0) { W = W1_0; R = BD; }
  else if (seg == 1) { W = W2_0; R = HD; }
  else if (seg == 2) { W = W1_1; R = BD; }
  else               { W = W2_1; R = HD; }
  const int C   = (R == BD) ? HD : BD;
  const int n   = id >> 13;
  const int rem = id & 8191;
  const int c   = rem / R;
  const int r   = rem - c * R;
  const unsigned short val = f2bf(W[(n * R + r) * C + c]);
  if (seg & 1) {
    const int hf  = r >> 6, st = (r >> 5) & 1, blk = (r >> 4) & 1;
    const int qq  = (r & 15) >> 2, e = r & 3;
    const int slot = hf * 64 + st * 32 + qq * 8 + blk * 4 + e;
    dst[seg * WSZ + n * 8192 + c * HD + (slot ^ ((c & 7) << 3))] = val;
  } else {
    dst[seg * WSZ + n * 8192 + c * BD + (r ^ ((c & 7) << 3))] = val;
  }
}

extern "C" void kernel_launch(void* const* d_in, const int* in_sizes, int n_in,
                              void* d_out, int out_size, void* d_ws, size_t ws_size,
                              hipStream_t stream) {
  const float* x    = (const float*)d_in[0];
  const float* W1_0 = (const float*)d_in[1];
  const float* b1_0 = (const float*)d_in[2];
  const float* W2_0 = (const float*)d_in[3];
  const float* b2_0 = (const float*)d_in[4];
  const float* W1_1 = (const float*)d_in[5];
  const float* b1_1 = (const float*)d_in[6];
  const float* W2_1 = (const float*)d_in[7];
  const float* b2_1 = (const float*)d_in[8];
  float* out = (float*)d_out;

  // ws layout: [Wt 2MB][Yt0 64MB transposed][Yt1 64MB block-tile]
  unsigned short* Wt  = (unsigned short*)d_ws;
  unsigned short* Yt0 = Wt + 4 * WSZ;
  unsigned short* Yt1 = Yt0 + (size_t)NB * TSZ;

  prep_w_all<<<4096, 256, 0, stream>>>(W1_0, W2_0, W1_1, W2_1, Wt);
  mlp0_k<<<2048, 256, 0, stream>>>(x, Yt0, Wt, Wt + WSZ, b1_0, b2_0);
  mlp1_k<<<2048, 256, 0, stream>>>(Yt0, Yt1, Wt + 2 * WSZ, Wt + 3 * WSZ, b1_1, b2_1);
  unpermute_k<<<2048, 256, 0, stream>>>(Yt1, out);
}

// Round 15
// 138.116 us; speedup vs baseline: 1.0224x; 1.0224x over previous
//
#include <hip/hip_runtime.h>

#define D    2048
#define NB   32
#define BD   64
#define HD   128
#define WSZ  (NB * HD * BD)     // 262144 elems per weight matrix
#define TSZ  (16384 * 64)       // 1048576 elems per activation block-tile

typedef __attribute__((ext_vector_type(8))) short short8;
typedef __attribute__((ext_vector_type(4))) float floatx4;

static __device__ __forceinline__ unsigned short f2bf(float f) {
  union { float f; unsigned u; } v; v.f = f;
  return (unsigned short)((v.u + 0x7FFFu + ((v.u >> 16) & 1u)) >> 16);
}
static __device__ __forceinline__ float bf2f(unsigned short h) {
  union { unsigned u; float f; } v; v.u = ((unsigned)h) << 16;
  return v.f;
}
static __device__ __forceinline__ unsigned fbits(float f) {
  union { float f; unsigned u; } v; v.f = f; return v.u;
}
// truncation bf16 (scalar) and bf16x2 pack (validated r9-r14, absmax 384 < 586)
static __device__ __forceinline__ unsigned short tbf(float f) {
  return (unsigned short)(fbits(f) >> 16);
}
static __device__ __forceinline__ unsigned pkt(float a, float b) {
  return __builtin_amdgcn_perm(fbits(b), fbits(a), 0x07060302u);
}
static __device__ __forceinline__ float fast_exp2(float x) {
  float r; asm("v_exp_f32 %0, %1" : "=v"(r) : "v"(x)); return r;
}
static __device__ __forceinline__ float fast_rcp(float x) {
  float r; asm("v_rcp_f32 %0, %1" : "=v"(r) : "v"(x)); return r;
}
// sigmoid-form GELU (validated r1-r14)
static __device__ __forceinline__ float gelu_f(float x) {
  float x2 = x * x;
  float w  = __builtin_fmaf(x2, -0.102943695f, -2.3022083f);
  float e  = fast_exp2(x * w);
  return x * fast_rcp(1.0f + e);
}

// ---------------------------------------------------------------------------
// mlp0 (unchanged from r14): 256 rows/WG, block-tile transposed output.
// ---------------------------------------------------------------------------
__global__ __launch_bounds__(256, 3) void mlp0_k(
    const float* __restrict__ xf,
    unsigned short* __restrict__ Yt0,        // [n][64][16384]
    const unsigned short* __restrict__ Wt1,
    const unsigned short* __restrict__ Wt2,
    const float* __restrict__ b1, const float* __restrict__ b2) {
  __shared__ unsigned short Wlds[16384];     // 32 KB
  __shared__ unsigned short Olds[64 * 128];  // 16 KB
  __shared__ float Blds[192];
  const int n     = blockIdx.x & 31;
  const int chunk = blockIdx.x >> 5;         // 0..63, 256 rows each
  const int t = threadIdx.x, l = t & 63, wv = t >> 6;
  const int lr = l & 15, q = l >> 4;
  const int sw = (lr & 7) << 3;
  const size_t rowbase = (size_t)chunk * 256;

  const unsigned short* s1 = Wt1 + n * 8192;
  const unsigned short* s2 = Wt2 + n * 8192;
  short8 sv1[4], sv2[4];
#pragma unroll
  for (int j = 0; j < 4; ++j) {
    sv1[j] = *(const short8*)&s1[(j * 256 + t) * 8];
    sv2[j] = *(const short8*)&s2[(j * 256 + t) * 8];
  }
  float bv = 0.f;
  if (t < 128)      bv = b1[n * HD + t];
  else if (t < 192) bv = b2[n * BD + (t - 128)];
  float4 uf[2][4];
#pragma unroll
  for (int p = 0; p < 2; ++p) {
    const float* xr = xf + (rowbase + p * 64 + wv * 16 + lr) * D + n * BD + q * 8;
    uf[p][0] = *(const float4*)(xr);      uf[p][1] = *(const float4*)(xr + 4);
    uf[p][2] = *(const float4*)(xr + 32); uf[p][3] = *(const float4*)(xr + 36);
  }
  asm volatile("" ::: "memory");
#pragma unroll
  for (int j = 0; j < 4; ++j) {
    *(short8*)&Wlds[(j * 256 + t) * 8]        = sv1[j];
    *(short8*)&Wlds[8192 + (j * 256 + t) * 8] = sv2[j];
  }
  if (t < 192) Blds[t] = bv;
  __syncthreads();

  const unsigned short* w1p0 = &Wlds[lr * 64 + ((q * 8) ^ sw)];
  const unsigned short* w1p1 = &Wlds[lr * 64 + ((32 + q * 8) ^ sw)];
  const unsigned short* w2p0 = &Wlds[8192 + lr * 128 + ((q * 8) ^ sw)];
  const unsigned short* w2p1 = &Wlds[8192 + lr * 128 + ((32 + q * 8) ^ sw)];

#pragma unroll
  for (int half = 0; half < 2; ++half) {
#pragma unroll
    for (int it = 0; it < 2; ++it) {
      const int i    = half * 2 + it;
      const int slot = i & 1;
      short8 xb0, xb1;
      {
        union { unsigned u[4]; short8 s; } c0, c1;
        c0.u[0] = pkt(uf[slot][0].x, uf[slot][0].y);
        c0.u[1] = pkt(uf[slot][0].z, uf[slot][0].w);
        c0.u[2] = pkt(uf[slot][1].x, uf[slot][1].y);
        c0.u[3] = pkt(uf[slot][1].z, uf[slot][1].w);
        c1.u[0] = pkt(uf[slot][2].x, uf[slot][2].y);
        c1.u[1] = pkt(uf[slot][2].z, uf[slot][2].w);
        c1.u[2] = pkt(uf[slot][3].x, uf[slot][3].y);
        c1.u[3] = pkt(uf[slot][3].z, uf[slot][3].w);
        xb0 = c0.s; xb1 = c1.s;
      }
      if (i < 2) {
        const float* xr = xf + (rowbase + (i + 2) * 64 + wv * 16 + lr) * D + n * BD + q * 8;
        uf[slot][0] = *(const float4*)(xr);      uf[slot][1] = *(const float4*)(xr + 4);
        uf[slot][2] = *(const float4*)(xr + 32); uf[slot][3] = *(const float4*)(xr + 36);
        asm volatile("" ::: "memory");
      }

      floatx4 acc2[4];
#pragma unroll
      for (int ot = 0; ot < 4; ++ot) {
        const float4 bb = *(const float4*)&Blds[128 + ot * 16 + q * 4];
        floatx4 v; v[0] = bb.x; v[1] = bb.y; v[2] = bb.z; v[3] = bb.w;
        acc2[ot] = v;
      }
#pragma unroll
      for (int hf = 0; hf < 2; ++hf) {
        floatx4 acc1[4];
#pragma unroll
        for (int ot = 0; ot < 4; ++ot) {
          const float4 bb = *(const float4*)&Blds[hf * 64 + ot * 16 + q * 4];
          floatx4 v; v[0] = bb.x; v[1] = bb.y; v[2] = bb.z; v[3] = bb.w;
          acc1[ot] = v;
        }
#pragma unroll
        for (int ot = 0; ot < 4; ++ot) {
          const int off = (hf * 64 + ot * 16) * 64;
          short8 a0 = *(const short8*)&w1p0[off];
          short8 a1 = *(const short8*)&w1p1[off];
          acc1[ot] = __builtin_amdgcn_mfma_f32_16x16x32_bf16(a0, xb0, acc1[ot], 0, 0, 0);
          acc1[ot] = __builtin_amdgcn_mfma_f32_16x16x32_bf16(a1, xb1, acc1[ot], 0, 0, 0);
        }
        union { unsigned u[4]; short8 s; } hb0, hb1;
        hb0.u[0] = pkt(gelu_f(acc1[0][0]), gelu_f(acc1[0][1]));
        hb0.u[1] = pkt(gelu_f(acc1[0][2]), gelu_f(acc1[0][3]));
        hb0.u[2] = pkt(gelu_f(acc1[1][0]), gelu_f(acc1[1][1]));
        hb0.u[3] = pkt(gelu_f(acc1[1][2]), gelu_f(acc1[1][3]));
        hb1.u[0] = pkt(gelu_f(acc1[2][0]), gelu_f(acc1[2][1]));
        hb1.u[1] = pkt(gelu_f(acc1[2][2]), gelu_f(acc1[2][3]));
        hb1.u[2] = pkt(gelu_f(acc1[3][0]), gelu_f(acc1[3][1]));
        hb1.u[3] = pkt(gelu_f(acc1[3][2]), gelu_f(acc1[3][3]));
#pragma unroll
        for (int ot = 0; ot < 4; ++ot) {
          const int off = ot * 16 * 128 + hf * 64;
          short8 w0 = *(const short8*)&w2p0[off];
          short8 w1 = *(const short8*)&w2p1[off];
          acc2[ot] = __builtin_amdgcn_mfma_f32_16x16x32_bf16(w0, hb0.s, acc2[ot], 0, 0, 0);
          ac2:;
          acc2[ot] = __builtin_amdgcn_mfma_f32_16x16x32_bf16(w1, hb1.s, acc2[ot], 0, 0, 0);
        }
      }
      const int rl = it * 64 + wv * 16 + lr;
#pragma unroll
      for (int ot = 0; ot < 4; ++ot) {
#pragma unroll
        for (int e = 0; e < 4; ++e) {
          const int fo = ot * 16 + q * 4 + e;
          Olds[fo * 128 + (rl ^ ((fo & 7) << 3))] = tbf(acc2[ot][e]);
        }
      }
    }
    __syncthreads();
    const int j = t & 63, w = t >> 6;
#pragma unroll
    for (int ii = 0; ii < 8; ++ii) {
      const int fo = w * 16 + ii * 2 + (j >> 5);
      const int r4 = (j & 31) * 4;
      const int G  = (fo & 7) << 3;
      uint2 v = *(const uint2*)&Olds[fo * 128 + (r4 ^ G)];
      *(uint2*)(Yt0 + (size_t)n * TSZ + (size_t)fo * 16384 + rowbase + half * 128 + r4) = v;
    }
    if (half == 0) __syncthreads();
  }
}

// ---------------------------------------------------------------------------
// mlp1 (unchanged from r14): permuted read from Yt0, block-tile Yt1 out.
// ---------------------------------------------------------------------------
__global__ __launch_bounds__(256, 3) void mlp1_k(
    const unsigned short* __restrict__ Yt0,   // [n][64][16384]
    unsigned short* __restrict__ Yt1,         // [np][16384][64]
    const unsigned short* __restrict__ Wt1,
    const unsigned short* __restrict__ Wt2,
    const float* __restrict__ b1, const float* __restrict__ b2) {
  __shared__ unsigned short Wlds[16384];       // 32 KB
  __shared__ unsigned short Xl[2 * 128 * 32];  // 16 KB
  __shared__ float Blds[192];
  const int np    = blockIdx.x & 31;
  const int chunk = blockIdx.x >> 5;
  const int t = threadIdx.x, l = t & 63, wv = t >> 6;
  const int lr = l & 15, q = l >> 4;
  const int sw = (lr & 7) << 3;
  const size_t rowbase = (size_t)chunk * 256;

  const unsigned short* s1 = Wt1 + np * 8192;
  const unsigned short* s2 = Wt2 + np * 8192;
  short8 sv1[4], sv2[4];
#pragma unroll
  for (int j = 0; j < 4; ++j) {
    sv1[j] = *(const short8*)&s1[(j * 256 + t) * 8];
    sv2[j] = *(const short8*)&s2[(j * 256 + t) * 8];
  }
  float bv = 0.f;
  if (t < 128)      bv = b1[np * HD + t];
  else if (t < 192) bv = b2[np * BD + (t - 128)];
  const int c = t >> 2, sub = t & 3;
  const int sp = c >> 5, sn = c & 31;
  const unsigned short* src0 = Yt0 + (size_t)sn * TSZ + (size_t)(sp * 32 + np) * 16384
                               + rowbase + sub * 32;
  short8 sx[4];
#pragma unroll
  for (int m = 0; m < 4; ++m) sx[m] = *(const short8*)(src0 + m * 8);

  asm volatile("" ::: "memory");
#pragma unroll
  for (int j = 0; j < 4; ++j) {
    *(short8*)&Wlds[(j * 256 + t) * 8]        = sv1[j];
    *(short8*)&Wlds[8192 + (j * 256 + t) * 8] = sv2[j];
  }
  if (t < 192) Blds[t] = bv;
#pragma unroll
  for (int m = 0; m < 4; ++m) {
#pragma unroll
    for (int k = 0; k < 8; ++k) {
      const int row = sub * 32 + m * 8 + k;
      Xl[sp * 4096 + row * 32 + (sn ^ (((row >> 1) & 3) << 3))] = (unsigned short)sx[m][k];
    }
  }
  __syncthreads();

  const unsigned short* w1p0 = &Wlds[lr * 64 + ((q * 8) ^ sw)];
  const unsigned short* w1p1 = &Wlds[lr * 64 + ((32 + q * 8) ^ sw)];
  const unsigned short* w2p0 = &Wlds[8192 + lr * 128 + ((q * 8) ^ sw)];
  const unsigned short* w2p1 = &Wlds[8192 + lr * 128 + ((32 + q * 8) ^ sw)];
  const int p = lr & 1;

#pragma unroll
  for (int half = 0; half < 2; ++half) {
    short8 sx2[4];
    if (half == 0) {
      const unsigned short* src1 = src0 + 128;
#pragma unroll
      for (int m = 0; m < 4; ++m) sx2[m] = *(const short8*)(src1 + m * 8);
      asm volatile("" ::: "memory");
    }
#pragma unroll
    for (int i = 0; i < 2; ++i) {
      const int rloc = (wv * 32 + i * 16 + lr) & ~1;
      const int g0   = ((rloc >> 1) & 3) << 3;
      short8 xb0 = *(const short8*)&Xl[p * 4096 + rloc * 32 + ((q * 8) ^ g0)];
      short8 xb1 = *(const short8*)&Xl[p * 4096 + (rloc + 1) * 32 + ((q * 8) ^ g0)];

      floatx4 acc2[4];
#pragma unroll
      for (int ot = 0; ot < 4; ++ot) {
        const float4 bb = *(const float4*)&Blds[128 + ot * 16 + q * 4];
        floatx4 v; v[0] = bb.x; v[1] = bb.y; v[2] = bb.z; v[3] = bb.w;
        acc2[ot] = v;
      }
#pragma unroll
      for (int hf = 0; hf < 2; ++hf) {
        floatx4 acc1[4];
#pragma unroll
        for (int ot = 0; ot < 4; ++ot) {
          const float4 bb = *(const float4*)&Blds[hf * 64 + ot * 16 + q * 4];
          floatx4 v; v[0] = bb.x; v[1] = bb.y; v[2] = bb.z; v[3] = bb.w;
          acc1[ot] = v;
        }
#pragma unroll
        for (int ot = 0; ot < 4; ++ot) {
          const int off = (hf * 64 + ot * 16) * 64;
          short8 a0 = *(const short8*)&w1p0[off];
          short8 a1 = *(const short8*)&w1p1[off];
          acc1[ot] = __builtin_amdgcn_mfma_f32_16x16x32_bf16(a0, xb0, acc1[ot], 0, 0, 0);
          acc1[ot] = __builtin_amdgcn_mfma_f32_16x16x32_bf16(a1, xb1, acc1[ot], 0, 0, 0);
        }
        union { unsigned u[4]; short8 s; } hb0, hb1;
        hb0.u[0] = pkt(gelu_f(acc1[0][0]), gelu_f(acc1[0][1]));
        hb0.u[1] = pkt(gelu_f(acc1[0][2]), gelu_f(acc1[0][3]));
        hb0.u[2] = pkt(gelu_f(acc1[1][0]), gelu_f(acc1[1][1]));
        hb0.u[3] = pkt(gelu_f(acc1[1][2]), gelu_f(acc1[1][3]));
        hb1.u[0] = pkt(gelu_f(acc1[2][0]), gelu_f(acc1[2][1]));
        hb1.u[1] = pkt(gelu_f(acc1[2][2]), gelu_f(acc1[2][3]));
        hb1.u[2] = pkt(gelu_f(acc1[3][0]), gelu_f(acc1[3][1]));
        hb1.u[3] = pkt(gelu_f(acc1[3][2]), gelu_f(acc1[3][3]));
#pragma unroll
        for (int ot = 0; ot < 4; ++ot) {
          const int off = ot * 16 * 128 + hf * 64;
          short8 w0 = *(const short8*)&w2p0[off];
          short8 w1 = *(const short8*)&w2p1[off];
          acc2[ot] = __builtin_amdgcn_mfma_f32_16x16x32_bf16(w0, hb0.s, acc2[ot], 0, 0, 0);
          acc2[ot] = __builtin_amdgcn_mfma_f32_16x16x32_bf16(w1, hb1.s, acc2[ot], 0, 0, 0);
        }
      }
      unsigned short* yo = Yt1 + (size_t)np * TSZ
                         + (rowbase + half * 128 + wv * 32 + i * 16 + lr) * 64;
#pragma unroll
      for (int ot = 0; ot < 4; ++ot) {
        ushort4 ov;
        ov.x = f2bf(acc2[ot][0]);
        ov.y = f2bf(acc2[ot][1]);
        ov.z = f2bf(acc2[ot][2]);
        ov.w = f2bf(acc2[ot][3]);
        *(ushort4*)&yo[ot * 16 + q * 4] = ov;
      }
    }
    if (half == 0) {
      __syncthreads();
#pragma unroll
      for (int m = 0; m < 4; ++m) {
#pragma unroll
        for (int k = 0; k < 8; ++k) {
          const int row = sub * 32 + m * 8 + k;
          Xl[sp * 4096 + row * 32 + (sn ^ (((row >> 1) & 3) << 3))] = (unsigned short)sx2[m][k];
        }
      }
      __syncthreads();
    }
  }
}

// ---------------------------------------------------------------------------
// unpermute_k (r15): 4 bands/WG (grid 512 = exactly 2 WG/CU), LDS double
// buffer; band k+1's global loads issued BEFORE band k's gather phase
// (fence-pinned) -> reads overlap the LDS-gather + f32-store phase.
// Gather mapping unchanged (validated r12-r14).
// ---------------------------------------------------------------------------
__global__ __launch_bounds__(256, 2) void unpermute_k(const unsigned short* __restrict__ Y,
                                                      float* __restrict__ out) {
  __shared__ unsigned short L[2][32 * 512];   // 64 KB
  const int t = threadIdx.x, w = t >> 6, j = t & 63;
  const int row = j >> 3;

  // stage band 0
  short8 v[8];
#pragma unroll
  for (int c = 0; c < 8; ++c) {
    const int n = w * 8 + c;
    v[c] = *(const short8*)(Y + (size_t)n * TSZ + ((size_t)blockIdx.x * 32) * 64 + j * 8);
  }
#pragma unroll
  for (int c = 0; c < 8; ++c) {
    const int n = w * 8 + c;
    const int gp = (j & 7) ^ ((n + row) & 7);
    *(short8*)&L[0][n * 512 + row * 64 + gp * 8] = v[c];
  }
  __syncthreads();

  for (int k = 0; k < 4; ++k) {
    // issue band k+1 loads before gather k (cover = gather + stores)
    short8 nv[8];
    if (k < 3) {
      const size_t r0n = (size_t)(blockIdx.x * 4 + k + 1) * 8;
#pragma unroll
      for (int c = 0; c < 8; ++c) {
        const int n = w * 8 + c;
        nv[c] = *(const short8*)(Y + (size_t)n * TSZ + r0n * 64 + j * 8);
      }
      asm volatile("" ::: "memory");
    }
    // gather band k from L[k&1] -> contiguous f32 rows
    const size_t r0 = (size_t)(blockIdx.x * 4 + k) * 8;
    const unsigned short* Lb = L[k & 1];
#pragma unroll
    for (int p = 0; p < 2; ++p) {
      const int rloc = w * 2 + p;
      float* op = out + (r0 + rloc) * (size_t)D;
#pragma unroll
      for (int i = 0; i < 8; ++i) {
        const int cbase = i * 256 + j * 4;
        float4 f;
#pragma unroll
        for (int e = 0; e < 4; ++e) {
          const int cc   = cbase + e;
          const int npp  = cc >> 6, fp = cc & 63;
          const int n    = fp & 31;
          const int srow = (rloc & ~1) | (fp >> 5);
          const int scol = (rloc & 1) * 32 + npp;
          const int g    = ((scol >> 3) ^ ((n + srow) & 7));
          const float vv = bf2f(Lb[n * 512 + srow * 64 + g * 8 + (scol & 7)]);
          if      (e == 0) f.x = vv;
          else if (e == 1) f.y = vv;
          else if (e == 2) f.z = vv;
          else             f.w = vv;
        }
        *(float4*)&op[cbase] = f;
      }
    }
    if (k < 3) {
      __syncthreads();   // all gathers of L[(k+1)&1]'s previous tenant done
#pragma unroll
      for (int c = 0; c < 8; ++c) {
        const int n = w * 8 + c;
        const int gp = (j & 7) ^ ((n + row) & 7);
        *(short8*)&L[(k + 1) & 1][n * 512 + row * 64 + gp * 8] = nv[c];
      }
      __syncthreads();
    }
  }
}

// ---------------------------------------------------------------------------
// prep (r15): coalesced. One WG per (seg, n): read W[n] (32KB f32) coalesced
// into LDS, then write transposed+swizzled(+slot-permuted for W2) bf16 image
// with 512B-contiguous instructions (inverse-mapping per output index).
// ---------------------------------------------------------------------------
__global__ __launch_bounds__(256) void prep_w_all(
    const float* __restrict__ W1_0, const float* __restrict__ W2_0,
    const float* __restrict__ W1_1, const float* __restrict__ W2_1,
    unsigned short* __restrict__ dst) {
  __shared__ float Lf[8192];   // 32 KB
  const int seg = blockIdx.x >> 5, n = blockIdx.x & 31;
  const float* W; int R;
  if      (seg == 0) { W = W1_0; R = BD; }
  else if (seg == 1) { W = W2_0; R = HD; }
  else if (seg == 2) { W = W1_1; R = BD; }
  else               { W = W2_1; R = HD; }
  const int t = threadIdx.x;
  const float* Wn = W + n * 8192;
#pragma unroll
  for (int i = 0; i < 32; ++i) Lf[i * 256 + t] = Wn[i * 256 + t];
  __syncthreads();
  const int C   = (R == BD) ? HD : BD;
  const int rsh = (R == BD) ? 6 : 7;
  unsigned short* dn = dst + seg * WSZ + n * 8192;
#pragma unroll
  for (int i = 0; i < 32; ++i) {
    const int o = i * 256 + t;
    const int cI = o >> rsh, s = o & (R - 1);
    int r = s ^ ((cI & 7) << 3);
    if (seg & 1) {   // invert W2 k-slot permutation (forward validated r7-r14)
      const int hf = r >> 6, st = (r >> 5) & 1, qq = (r >> 3) & 3;
      const int blk = (r >> 2) & 1, e = r & 3;
      r = hf * 64 + st * 32 + blk * 16 + qq * 4 + e;
    }
    dn[o] = f2bf(Lf[r * C + cI]);
  }
}

extern "C" void kernel_launch(void* const* d_in, const int* in_sizes, int n_in,
                              void* d_out, int out_size, void* d_ws, size_t ws_size,
                              hipStream_t stream) {
  const float* x    = (const float*)d_in[0];
  const float* W1_0 = (const float*)d_in[1];
  const float* b1_0 = (const float*)d_in[2];
  const float* W2_0 = (const float*)d_in[3];
  const float* b2_0 = (const float*)d_in[4];
  const float* W1_1 = (const float*)d_in[5];
  const float* b1_1 = (const float*)d_in[6];
  const float* W2_1 = (const float*)d_in[7];
  const float* b2_1 = (const float*)d_in[8];
  float* out = (float*)d_out;

  // ws layout: [Wt 2MB][Yt0 64MB transposed][Yt1 64MB block-tile]
  unsigned short* Wt  = (unsigned short*)d_ws;
  unsigned short* Yt0 = Wt + 4 * WSZ;
  unsigned short* Yt1 = Yt0 + (size_t)NB * TSZ;

  prep_w_all<<<128, 256, 0, stream>>>(W1_0, W2_0, W1_1, W2_1, Wt);
  mlp0_k<<<2048, 256, 0, stream>>>(x, Yt0, Wt, Wt + WSZ, b1_0, b2_0);
  mlp1_k<<<2048, 256, 0, stream>>>(Yt0, Yt1, Wt + 2 * WSZ, Wt + 3 * WSZ, b1_1, b2_1);
  unpermute_k<<<512, 256, 0, stream>>>(Yt1, out);
}